// Round 15
// baseline (218.038 us; speedup 1.0000x reference)
//
#include <hip/hip_runtime.h>
#include <stdint.h>

#define S_LEN 8192
#define DIM   1024
#define NH    16
#define HD    64
#define WIN   1024
#define GTOK  256
#define QKV_STRIDE (3 * DIM)

typedef __attribute__((ext_vector_type(8))) short bf16x8;
typedef __attribute__((ext_vector_type(4))) float f32x4;
typedef __attribute__((ext_vector_type(16))) float f32x16;
typedef unsigned short u16;
typedef uint32_t u32;

__device__ __forceinline__ u16 f2bf(float f) {
  union { float f; uint32_t u; } v; v.f = f;
  uint32_t r = v.u + 0x7fffu + ((v.u >> 16) & 1u);
  return (u16)(r >> 16);
}
__device__ __forceinline__ float bf2f(u16 b) {
  union { uint32_t u; float f; } v; v.u = ((uint32_t)b) << 16;
  return v.f;
}
__device__ __forceinline__ uint32_t cvtpk(float a, float b) {
  uint32_t r;
  asm("v_cvt_pk_bf16_f32 %0, %1, %2" : "=v"(r) : "v"(a), "v"(b));
  return r;
}

__device__ __forceinline__ void gload_lds16(const void* g, void* l) {
  __builtin_amdgcn_global_load_lds((const __attribute__((address_space(1))) void*)g,
                                   (__attribute__((address_space(3))) void*)l, 16, 0, 0);
}

// ---------------- RMSNorm + scorer (+ cnt zeroing for topk) ----------------
__global__ __launch_bounds__(256) void rmsnorm_score_kernel(
    const float* __restrict__ x, const float* __restrict__ nw,
    const float* __restrict__ sw, const float* __restrict__ sb,
    u16* __restrict__ h, float* __restrict__ scores, int* __restrict__ cnt) {
  int row = blockIdx.x, tid = threadIdx.x;
  const float4* xr = (const float4*)(x + (size_t)row * DIM);
  float4 v = xr[tid];
  float ss = v.x * v.x + v.y * v.y + v.z * v.z + v.w * v.w;
#pragma unroll
  for (int o = 32; o >= 1; o >>= 1) ss += __shfl_xor(ss, o);
  __shared__ float red[4], red2[4];
  int wv = tid >> 6;
  if ((tid & 63) == 0) red[wv] = ss;
  __syncthreads();
  ss = red[0] + red[1] + red[2] + red[3];
  float rn = rsqrtf(ss * (1.0f / DIM) + 1e-6f);
  float4 w4 = ((const float4*)nw)[tid];
  float h0 = v.x * rn * w4.x, h1 = v.y * rn * w4.y;
  float h2 = v.z * rn * w4.z, h3 = v.w * rn * w4.w;
  uint64_t pack = (uint64_t)f2bf(h0) | ((uint64_t)f2bf(h1) << 16) |
                  ((uint64_t)f2bf(h2) << 32) | ((uint64_t)f2bf(h3) << 48);
  *(uint64_t*)(h + (size_t)row * DIM + tid * 4) = pack;
  float4 s4 = ((const float4*)sw)[tid];
  float sc = h0 * s4.x + h1 * s4.y + h2 * s4.z + h3 * s4.w;
#pragma unroll
  for (int o = 32; o >= 1; o >>= 1) sc += __shfl_xor(sc, o);
  if ((tid & 63) == 0) red2[wv] = sc;
  __syncthreads();
  if (tid == 0) {
    scores[row] = red2[0] + red2[1] + red2[2] + red2[3] + sb[0];
    cnt[row] = 0;
  }
}

// ---------------- weight transpose + bf16 convert ----------------
__global__ __launch_bounds__(256) void transpose_w_kernel(
    const float* __restrict__ wq, const float* __restrict__ wk,
    const float* __restrict__ wv, const float* __restrict__ wo,
    u16* __restrict__ wqkvT, u16* __restrict__ woutT) {
  __shared__ float tile[32][33];
  int z = blockIdx.z;
  const float* src = (z == 0) ? wq : (z == 1) ? wk : (z == 2) ? wv : wo;
  u16* dst = (z < 3) ? (wqkvT + (size_t)z * DIM * DIM) : woutT;
  int tx = threadIdx.x, ty = threadIdx.y;  // 32 x 8
  int n0 = blockIdx.x * 32, k0 = blockIdx.y * 32;
#pragma unroll
  for (int i = 0; i < 4; i++)
    tile[ty + i * 8][tx] = src[(size_t)(k0 + ty + i * 8) * DIM + n0 + tx];
  __syncthreads();
#pragma unroll
  for (int i = 0; i < 4; i++)
    dst[(size_t)(n0 + ty + i * 8) * DIM + k0 + tx] = f2bf(tile[tx][ty + i * 8]);
}

// ---------------- exact top-G by distributed rank counting ----------------
__global__ __launch_bounds__(256) void topk_count_kernel(
    const float* __restrict__ scores, int* __restrict__ cnt) {
  __shared__ float sj[1024];
  int jbase = blockIdx.y * 1024;
  for (int t = threadIdx.x; t < 1024; t += 256) sj[t] = scores[jbase + t];
  __syncthreads();
  int i = blockIdx.x * 256 + threadIdx.x;
  float my = scores[i];
  int c = 0;
  const float4* s4 = (const float4*)sj;
#pragma unroll 4
  for (int j = 0; j < 256; j++) {
    float4 v = s4[j];
    int b = jbase + j * 4;
    c += (v.x > my) || (v.x == my && (b + 0) < i);
    c += (v.y > my) || (v.y == my && (b + 1) < i);
    c += (v.z > my) || (v.z == my && (b + 2) < i);
    c += (v.w > my) || (v.w == my && (b + 3) < i);
  }
  if (c) atomicAdd(&cnt[i], c);
}

__global__ __launch_bounds__(256) void topk_scatter_kernel(
    const int* __restrict__ cnt, int* __restrict__ gidx) {
  int i = blockIdx.x * 256 + threadIdx.x;
  int c = cnt[i];
  if (c < GTOK) gidx[c] = i;
}

// ---------------- gather top-G K/V rows ----------------
__global__ __launch_bounds__(128) void gather_kernel(
    const u16* __restrict__ qkv, const int* __restrict__ gidx,
    u16* __restrict__ kg, u16* __restrict__ vg) {
  int g = blockIdx.x, t = threadIdx.x;
  size_t src = (size_t)gidx[g] * QKV_STRIDE;
  *(bf16x8*)(kg + (size_t)g * DIM + t * 8) = *(const bf16x8*)(qkv + src + DIM + t * 8);
  *(bf16x8*)(vg + (size_t)g * DIM + t * 8) = *(const bf16x8*)(qkv + src + 2 * DIM + t * 8);
}

// ---------------- GEMM 256Mx128N tile, 8 waves, BK=64, 3-buf, 4-phase interleave ----------------
// Per K-tile: 4 phases of {ds_read this phase's frags | issue half of t+2 staging ->
// s_barrier -> lgkmcnt(0) -> setprio + 8-MFMA cluster}. Counted vmcnt(6) tile-end
// handoff unchanged (t+2's 6 loads stay in flight). m201-pattern fine interleave.
template <int RESID>
__global__ __launch_bounds__(512, 2) void gemm256_kernel(
    const u16* __restrict__ A, const u16* __restrict__ B,
    u16* __restrict__ Cb, float* __restrict__ Cf, const float* __restrict__ X,
    int M, int N, int K) {
  __shared__ __align__(16) u16 As[3][256 * 64];
  __shared__ __align__(16) u16 Bs[3][128 * 64];
  const int tid = threadIdx.x;
  const int wave = tid >> 6, lane = tid & 63;
  const int l15 = lane & 15, l4 = lane >> 4;
  const int wr = wave >> 1, wc = wave & 1;  // 4M x 2N wave grid, 64x64 per wave
  const int mbase = blockIdx.x * 256, nbase = blockIdx.y * 128;
  const int srow = lane >> 3, schunk = lane & 7;
  const int gcol = (schunk ^ srow) * 8;

  auto stage = [&](int tt, int b) {  // full-tile stage (prologue only)
    const int kt = tt << 6;
#pragma unroll
    for (int q = 0; q < 4; q++) {
      int row = wave * 32 + q * 8;
      gload_lds16(A + (size_t)(mbase + row + srow) * K + kt + gcol, &As[b][row * 64]);
    }
#pragma unroll
    for (int q = 0; q < 2; q++) {
      int row = wave * 16 + q * 8;
      gload_lds16(B + (size_t)(nbase + row + srow) * K + kt + gcol, &Bs[b][row * 64]);
    }
  };
  auto stage_half = [&](int tt, int b, int hf) {  // 2 A-loads + 1 B-load
    const int kt = tt << 6;
#pragma unroll
    for (int q = 2 * hf; q < 2 * hf + 2; q++) {
      int row = wave * 32 + q * 8;
      gload_lds16(A + (size_t)(mbase + row + srow) * K + kt + gcol, &As[b][row * 64]);
    }
    int row = wave * 16 + hf * 8;
    gload_lds16(B + (size_t)(nbase + row + srow) * K + kt + gcol, &Bs[b][row * 64]);
  };

  const int nt = K >> 6;
  f32x4 acc[4][4] = {};

  stage(0, 0);
  stage(1, 1);
  asm volatile("s_waitcnt vmcnt(6)" ::: "memory");
  __builtin_amdgcn_s_barrier();
  __builtin_amdgcn_sched_barrier(0);

  int cur = 0;
  for (int t = 0; t < nt; t++) {
    int pre = cur + 2; if (pre >= 3) pre -= 3;
    const u16* Ab = &As[cur][0];
    const u16* Bb = &Bs[cur][0];
    bf16x8 bfr[4][2], af[4][2];

    // ---- phase 1: frags for (mi 0-1) x (nf 0-1); stage half 0 ----
#pragma unroll
    for (int nf = 0; nf < 2; nf++) {
      int row = wc * 64 + nf * 16 + l15;
#pragma unroll
      for (int kk = 0; kk < 2; kk++)
        bfr[nf][kk] = *(const bf16x8*)(Bb + row * 64 + (((kk * 4 + l4) ^ (l15 & 7)) * 8));
    }
#pragma unroll
    for (int mi = 0; mi < 2; mi++) {
      int row = wr * 64 + mi * 16 + l15;
#pragma unroll
      for (int kk = 0; kk < 2; kk++)
        af[mi][kk] = *(const bf16x8*)(Ab + row * 64 + (((kk * 4 + l4) ^ (l15 & 7)) * 8));
    }
    if (t + 2 < nt) stage_half(t + 2, pre, 0);
    __builtin_amdgcn_s_barrier();
    asm volatile("s_waitcnt lgkmcnt(0)" ::: "memory");
    __builtin_amdgcn_sched_barrier(0);
    __builtin_amdgcn_s_setprio(1);
#pragma unroll
    for (int mi = 0; mi < 2; mi++)
#pragma unroll
      for (int nf = 0; nf < 2; nf++)
#pragma unroll
        for (int kk = 0; kk < 2; kk++)
          acc[mi][nf] = __builtin_amdgcn_mfma_f32_16x16x32_bf16(af[mi][kk], bfr[nf][kk],
                                                                acc[mi][nf], 0, 0, 0);
    __builtin_amdgcn_s_setprio(0);

    // ---- phase 2: bfr 2-3; stage half 1; MFMA (mi 0-1) x (nf 2-3) ----
#pragma unroll
    for (int nf = 2; nf < 4; nf++) {
      int row = wc * 64 + nf * 16 + l15;
#pragma unroll
      for (int kk = 0; kk < 2; kk++)
        bfr[nf][kk] = *(const bf16x8*)(Bb + row * 64 + (((kk * 4 + l4) ^ (l15 & 7)) * 8));
    }
    if (t + 2 < nt) stage_half(t + 2, pre, 1);
    __builtin_amdgcn_s_barrier();
    asm volatile("s_waitcnt lgkmcnt(0)" ::: "memory");
    __builtin_amdgcn_sched_barrier(0);
    __builtin_amdgcn_s_setprio(1);
#pragma unroll
    for (int mi = 0; mi < 2; mi++)
#pragma unroll
      for (int nf = 2; nf < 4; nf++)
#pragma unroll
        for (int kk = 0; kk < 2; kk++)
          acc[mi][nf] = __builtin_amdgcn_mfma_f32_16x16x32_bf16(af[mi][kk], bfr[nf][kk],
                                                                acc[mi][nf], 0, 0, 0);
    __builtin_amdgcn_s_setprio(0);

    // ---- phase 3: af 2-3; MFMA (mi 2-3) x (nf 0-1) ----
#pragma unroll
    for (int mi = 2; mi < 4; mi++) {
      int row = wr * 64 + mi * 16 + l15;
#pragma unroll
      for (int kk = 0; kk < 2; kk++)
        af[mi][kk] = *(const bf16x8*)(Ab + row * 64 + (((kk * 4 + l4) ^ (l15 & 7)) * 8));
    }
    __builtin_amdgcn_s_barrier();
    asm volatile("s_waitcnt lgkmcnt(0)" ::: "memory");
    __builtin_amdgcn_sched_barrier(0);
    __builtin_amdgcn_s_setprio(1);
#pragma unroll
    for (int mi = 2; mi < 4; mi++)
#pragma unroll
      for (int nf = 0; nf < 2; nf++)
#pragma unroll
        for (int kk = 0; kk < 2; kk++)
          acc[mi][nf] = __builtin_amdgcn_mfma_f32_16x16x32_bf16(af[mi][kk], bfr[nf][kk],
                                                                acc[mi][nf], 0, 0, 0);
    __builtin_amdgcn_s_setprio(0);

    // ---- phase 4: MFMA (mi 2-3) x (nf 2-3) ----
    __builtin_amdgcn_s_setprio(1);
#pragma unroll
    for (int mi = 2; mi < 4; mi++)
#pragma unroll
      for (int nf = 2; nf < 4; nf++)
#pragma unroll
        for (int kk = 0; kk < 2; kk++)
          acc[mi][nf] = __builtin_amdgcn_mfma_f32_16x16x32_bf16(af[mi][kk], bfr[nf][kk],
                                                                acc[mi][nf], 0, 0, 0);
    __builtin_amdgcn_s_setprio(0);

    // ---- tile end: next buffer's loads landed; t+2's stay in flight ----
    if (t + 1 < nt) {
      if (t + 2 < nt) asm volatile("s_waitcnt vmcnt(6)" ::: "memory");
      else            asm volatile("s_waitcnt vmcnt(0)" ::: "memory");
      __builtin_amdgcn_s_barrier();
      __builtin_amdgcn_sched_barrier(0);
    }
    cur = (cur + 1 == 3) ? 0 : cur + 1;
  }

#pragma unroll
  for (int mi = 0; mi < 4; mi++) {
#pragma unroll
    for (int nf = 0; nf < 4; nf++) {
#pragma unroll
      for (int r = 0; r < 4; r++) {
        int row = mbase + wr * 64 + mi * 16 + l4 * 4 + r;
        int col = nbase + wc * 64 + nf * 16 + l15;
        float v = acc[mi][nf][r];
        if (RESID) Cf[(size_t)row * N + col] = X[(size_t)row * N + col] + v;
        else       Cb[(size_t)row * N + col] = f2bf(v);
      }
    }
  }
}

// ---------------- fused flash attention (r14 structure, 2-shfl pack exchange) ----------------
__global__ __launch_bounds__(512) void attn_kernel(
    const u16* __restrict__ qkv, const u16* __restrict__ kg,
    const u16* __restrict__ vg, const int* __restrict__ gidx,
    u16* __restrict__ o) {
  __shared__ u16 kT[2][128][72];   // [buf][key][d] (+8 pad)
  __shared__ u16 vT[2][64][136];   // [buf][d][key-halfXOR] (+8 pad)
  __shared__ int gposLds[2][128];
  const int tid = threadIdx.x, wave = tid >> 6, lane = tid & 63;
  const int l31 = lane & 31, hi = lane >> 5;
  const int win = blockIdx.x >> 1, pair = blockIdx.x & 1;
  const int wbase = win * WIN;
  const int hoff = blockIdx.y * HD;

  const int skey = tid >> 3, sd8 = (tid & 7) * 8;
  const int vcol = skey ^ ((sd8 >> 4) << 4);

  bf16x8 nk0, nk1, nv0, nv1;
  int ng = 0;
  {
    const u16* b0 = qkv + (size_t)(wbase + skey) * QKV_STRIDE + hoff + sd8;
    const u16* b1 = qkv + (size_t)(wbase + 64 + skey) * QKV_STRIDE + hoff + sd8;
    nk0 = *(const bf16x8*)(b0 + DIM);     nv0 = *(const bf16x8*)(b0 + 2 * DIM);
    nk1 = *(const bf16x8*)(b1 + DIM);     nv1 = *(const bf16x8*)(b1 + 2 * DIM);
  }

  for (int sp = 0; sp < 2; sp++) {
    const int j = sp ? (3 - pair) : pair;
    const int qsbase = wbase + j * 256;
    const int nLocal = (j + 1) * 2;
    const int nTiles = nLocal + GTOK / 128;
    const int qrow = qsbase + wave * 32 + l31;
    const int qwmax = qsbase + wave * 32 + 31;

    bf16x8 qf[4];
    {
      const float SC2 = 0.125f * 1.44269504088896f;
      const u16* qptr = qkv + (size_t)qrow * QKV_STRIDE + hoff + hi * 8;
#pragma unroll
      for (int ks = 0; ks < 4; ks++) {
        bf16x8 raw = *(const bf16x8*)(qptr + ks * 16);
        bf16x8 sc;
#pragma unroll
        for (int jj = 0; jj < 8; jj++) sc[jj] = (short)f2bf(bf2f((u16)raw[jj]) * SC2);
        qf[ks] = sc;
      }
    }

    f32x16 acc0 = {}, acc1 = {};
    float mr = -3.0e38f, lr = 0.f;

    __syncthreads();

    for (int t = 0; t < nTiles; t++) {
      const int p = t & 1;
      const bool isLocal = (t < nLocal);
      *(bf16x8*)(&kT[p][skey][sd8]) = nk0;
      *(bf16x8*)(&kT[p][64 + skey][sd8]) = nk1;
#pragma unroll
      for (int jj = 0; jj < 8; jj++) {
        vT[p][sd8 + jj][vcol] = (u16)nv0[jj];
        vT[p][sd8 + jj][64 + vcol] = (u16)nv1[jj];
      }
      if (!isLocal && tid < 128) gposLds[p][tid] = ng;
      {
        const int nt = t + 1;
        const u16 *k0s = nullptr, *k1s = nullptr, *v0s = nullptr, *v1s = nullptr;
        if (nt < nLocal) {
          const u16* b0 = qkv + (size_t)(wbase + nt * 128 + skey) * QKV_STRIDE + hoff + sd8;
          const u16* b1 = b0 + (size_t)64 * QKV_STRIDE;
          k0s = b0 + DIM; v0s = b0 + 2 * DIM;
          k1s = b1 + DIM; v1s = b1 + 2 * DIM;
        } else if (nt < nTiles) {
          size_t g0 = (size_t)((nt - nLocal) * 128 + skey) * DIM + hoff + sd8;
          k0s = kg + g0; v0s = vg + g0;
          k1s = kg + g0 + (size_t)64 * DIM; v1s = vg + g0 + (size_t)64 * DIM;
          if (tid < 128) ng = gidx[(nt - nLocal) * 128 + tid];
        } else if (sp == 0) {
          const u16* b0 = qkv + (size_t)(wbase + skey) * QKV_STRIDE + hoff + sd8;
          const u16* b1 = b0 + (size_t)64 * QKV_STRIDE;
          k0s = b0 + DIM; v0s = b0 + 2 * DIM;
          k1s = b1 + DIM; v1s = b1 + 2 * DIM;
        }
        if (k0s) {
          nk0 = *(const bf16x8*)(k0s); nv0 = *(const bf16x8*)(v0s);
          nk1 = *(const bf16x8*)(k1s); nv1 = *(const bf16x8*)(v1s);
        }
      }
      __syncthreads();

#pragma unroll
      for (int sub = 0; sub < 2; sub++) {
        const int tbase = wbase + t * 128 + sub * 64;
        if (isLocal && tbase > qwmax) continue;

        float sv[32];
        __builtin_amdgcn_s_setprio(1);
#pragma unroll
        for (int kb = 0; kb < 2; kb++) {
          const u16* krow = &kT[p][sub * 64 + kb * 32 + l31][hi * 8];
          bf16x8 k0 = *(const bf16x8*)(krow);
          bf16x8 k1 = *(const bf16x8*)(krow + 16);
          bf16x8 k2 = *(const bf16x8*)(krow + 32);
          bf16x8 k3 = *(const bf16x8*)(krow + 48);
          f32x16 z = {};
          z = __builtin_amdgcn_mfma_f32_32x32x16_bf16(k0, qf[0], z, 0, 0, 0);
          z = __builtin_amdgcn_mfma_f32_32x32x16_bf16(k1, qf[1], z, 0, 0, 0);
          z = __builtin_amdgcn_mfma_f32_32x32x16_bf16(k2, qf[2], z, 0, 0, 0);
          z = __builtin_amdgcn_mfma_f32_32x32x16_bf16(k3, qf[3], z, 0, 0, 0);
#pragma unroll
          for (int r = 0; r < 16; r++) sv[kb * 16 + r] = z[r];
        }
        __builtin_amdgcn_s_setprio(0);

        if (isLocal) {
          const int lim = qrow - tbase;
          if (lim < 63) {
#pragma unroll
            for (int kb = 0; kb < 2; kb++)
#pragma unroll
              for (int r = 0; r < 16; r++) {
                int crow = kb * 32 + (r & 3) + 8 * (r >> 2) + 4 * hi;
                if (crow > lim) sv[kb * 16 + r] = -3.0e38f;
              }
          }
        } else {
#pragma unroll
          for (int kb = 0; kb < 2; kb++)
#pragma unroll
            for (int r = 0; r < 16; r++) {
              int kpos = gposLds[p][sub * 64 + kb * 32 + (r & 3) + 8 * (r >> 2) + 4 * hi];
              if (kpos > qrow) sv[kb * 16 + r] = -3.0e38f;
            }
        }

        float m0 = sv[0], m1 = sv[1], m2 = sv[2], m3 = sv[3];
#pragma unroll
        for (int i = 4; i < 32; i += 4) {
          m0 = fmaxf(m0, sv[i]);     m1 = fmaxf(m1, sv[i + 1]);
          m2 = fmaxf(m2, sv[i + 2]); m3 = fmaxf(m3, sv[i + 3]);
        }
        float vmax = fmaxf(fmaxf(m0, m1), fmaxf(m2, m3));
        vmax = fmaxf(vmax, __shfl_xor(vmax, 32));
        if (__any(vmax > mr + 11.0f)) {
          float mn = fmaxf(mr, vmax);
          float al = exp2f(mr - mn);
          lr *= al;
          mr = mn;
#pragma unroll
          for (int i = 0; i < 16; i++) { acc0[i] *= al; acc1[i] *= al; }
        }
        float s0 = 0.f, s1 = 0.f, s2 = 0.f, s3 = 0.f;
#pragma unroll
        for (int i = 0; i < 32; i += 4) {
          float p0 = exp2f(sv[i] - mr),     p1 = exp2f(sv[i + 1] - mr);
          float p2 = exp2f(sv[i + 2] - mr), p3 = exp2f(sv[i + 3] - mr);
          sv[i] = p0; sv[i + 1] = p1; sv[i + 2] = p2; sv[i + 3] = p3;
          s0 += p0; s1 += p1; s2 += p2; s3 += p3;
        }
        float ps = (s0 + s1) + (s2 + s3);
        ps += __shfl_xor(ps, 32);
        lr += ps;

        // ---- build P B-fragments: 2 shfls per q4 (lane consumes only partner's half) ----
        bf16x8 pf[4];
#pragma unroll
        for (int q4 = 0; q4 < 4; q4++) {
          int b = q4 * 8;
          uint32_t w0 = cvtpk(sv[b + 0], sv[b + 1]);
          uint32_t w1 = cvtpk(sv[b + 2], sv[b + 3]);
          uint32_t w2 = cvtpk(sv[b + 4], sv[b + 5]);
          uint32_t w3 = cvtpk(sv[b + 6], sv[b + 7]);
          uint32_t x1 = hi ? w0 : w2;
          uint32_t x2 = hi ? w1 : w3;
          uint32_t r1 = (uint32_t)__shfl_xor((int)x1, 32);
          uint32_t r2 = (uint32_t)__shfl_xor((int)x2, 32);
          union { uint32_t w[4]; bf16x8 v; } u;
          u.w[0] = hi ? r1 : w0;
          u.w[1] = hi ? r2 : w1;
          u.w[2] = hi ? w2 : r1;
          u.w[3] = hi ? w3 : r2;
          pf[q4] = u.v;
        }

        __builtin_amdgcn_s_setprio(1);
#pragma unroll
        for (int dblk = 0; dblk < 2; dblk++) {
          const int swz = (dblk * 2 + (l31 >> 4)) << 4;
          const u16* vrow = &vT[p][dblk * 32 + l31][sub * 64];
          f32x16 a = dblk ? acc1 : acc0;
#pragma unroll
          for (int ksg = 0; ksg < 4; ksg++) {
            bf16x8 vf = *(const bf16x8*)(vrow + ((ksg * 16 + hi * 8) ^ swz));
            a = __builtin_amdgcn_mfma_f32_32x32x16_bf16(vf, pf[ksg], a, 0, 0, 0);
          }
          if (dblk) acc1 = a; else acc0 = a;
        }
        __builtin_amdgcn_s_setprio(0);
      }
    }

    float inv = 1.0f / lr;
#pragma unroll
    for (int dblk = 0; dblk < 2; dblk++) {
      f32x16 a = dblk ? acc1 : acc0;
#pragma unroll
      for (int g = 0; g < 4; g++) {
        uint64_t pk = (uint64_t)f2bf(a[g * 4 + 0] * inv)
                    | ((uint64_t)f2bf(a[g * 4 + 1] * inv) << 16)
                    | ((uint64_t)f2bf(a[g * 4 + 2] * inv) << 32)
                    | ((uint64_t)f2bf(a[g * 4 + 3] * inv) << 48);
        *(uint64_t*)(o + (size_t)qrow * DIM + hoff + dblk * 32 + g * 8 + 4 * hi) = pk;
      }
    }
  }
}

// ---------------- launch ----------------
extern "C" void kernel_launch(void* const* d_in, const int* in_sizes, int n_in,
                              void* d_out, int out_size, void* d_ws, size_t ws_size,
                              hipStream_t stream) {
  const float* x  = (const float*)d_in[0];
  const float* nw = (const float*)d_in[1];
  const float* wq = (const float*)d_in[2];
  const float* wk = (const float*)d_in[3];
  const float* wv = (const float*)d_in[4];
  const float* wo = (const float*)d_in[5];
  const float* sw = (const float*)d_in[6];
  const float* sb = (const float*)d_in[7];
  float* out = (float*)d_out;

  char* ws = (char*)d_ws;
  size_t off = 0;
  auto alloc = [&](size_t b) {
    char* p = ws + off;
    off = (off + b + 255) & ~(size_t)255;
    return p;
  };
  u16*   h      = (u16*)alloc((size_t)S_LEN * DIM * 2);
  u16*   wqkvT  = (u16*)alloc((size_t)3 * DIM * DIM * 2);
  u16*   woutT  = (u16*)alloc((size_t)DIM * DIM * 2);
  u16*   qkv    = (u16*)alloc((size_t)S_LEN * 3 * DIM * 2);
  u16*   obuf   = (u16*)alloc((size_t)S_LEN * DIM * 2);
  float* scores = (float*)alloc((size_t)S_LEN * 4);
  int*   cnt    = (int*)alloc((size_t)S_LEN * 4);
  int*   gidx   = (int*)alloc((size_t)GTOK * 4);
  u16*   kgbuf  = (u16*)alloc((size_t)GTOK * DIM * 2);
  u16*   vgbuf  = (u16*)alloc((size_t)GTOK * DIM * 2);

  transpose_w_kernel<<<dim3(32, 32, 4), dim3(32, 8), 0, stream>>>(wq, wk, wv, wo, wqkvT, woutT);
  rmsnorm_score_kernel<<<dim3(S_LEN), dim3(256), 0, stream>>>(x, nw, sw, sb, h, scores, cnt);
  topk_count_kernel<<<dim3(32, 8), dim3(256), 0, stream>>>(scores, cnt);
  topk_scatter_kernel<<<dim3(S_LEN / 256), dim3(256), 0, stream>>>(cnt, gidx);
  gemm256_kernel<0><<<dim3(32, 24), dim3(512), 0, stream>>>(h, wqkvT, qkv, nullptr, nullptr,
                                                            S_LEN, 3 * DIM, DIM);
  gather_kernel<<<dim3(GTOK), dim3(128), 0, stream>>>(qkv, gidx, kgbuf, vgbuf);
  attn_kernel<<<dim3(16, NH), dim3(512), 0, stream>>>(qkv, kgbuf, vgbuf, gidx, obuf);
  gemm256_kernel<1><<<dim3(32, 8), dim3(512), 0, stream>>>(obuf, woutT, nullptr, out, x,
                                                           S_LEN, DIM, DIM);
}

// Round 16
// 212.321 us; speedup vs baseline: 1.0269x; 1.0269x over previous
//
#include <hip/hip_runtime.h>
#include <stdint.h>

#define S_LEN 8192
#define DIM   1024
#define NH    16
#define HD    64
#define WIN   1024
#define GTOK  256
#define QKV_STRIDE (3 * DIM)

typedef __attribute__((ext_vector_type(8))) short bf16x8;
typedef __attribute__((ext_vector_type(4))) float f32x4;
typedef __attribute__((ext_vector_type(16))) float f32x16;
typedef unsigned short u16;
typedef uint32_t u32;

__device__ __forceinline__ u16 f2bf(float f) {
  union { float f; uint32_t u; } v; v.f = f;
  uint32_t r = v.u + 0x7fffu + ((v.u >> 16) & 1u);
  return (u16)(r >> 16);
}
__device__ __forceinline__ float bf2f(u16 b) {
  union { uint32_t u; float f; } v; v.u = ((uint32_t)b) << 16;
  return v.f;
}
__device__ __forceinline__ uint32_t cvtpk(float a, float b) {
  uint32_t r;
  asm("v_cvt_pk_bf16_f32 %0, %1, %2" : "=v"(r) : "v"(a), "v"(b));
  return r;
}

__device__ __forceinline__ void gload_lds16(const void* g, void* l) {
  __builtin_amdgcn_global_load_lds((const __attribute__((address_space(1))) void*)g,
                                   (__attribute__((address_space(3))) void*)l, 16, 0, 0);
}

// ---------------- fused prep: weight transpose (blocks 0..4095) + RMSNorm/scorer ----------------
__global__ __launch_bounds__(256) void prep_kernel(
    const float* __restrict__ x, const float* __restrict__ nw,
    const float* __restrict__ sw, const float* __restrict__ sb,
    const float* __restrict__ wq, const float* __restrict__ wk,
    const float* __restrict__ wv, const float* __restrict__ wo,
    u16* __restrict__ h, float* __restrict__ scores, int* __restrict__ cnt,
    u16* __restrict__ wqkvT, u16* __restrict__ woutT) {
  const int b = blockIdx.x, tid = threadIdx.x;
  if (b < 4096) {  // ---- weight transpose + bf16 convert ----
    __shared__ float tile[32][33];
    const int z = b >> 10, rem = b & 1023;
    const int n0 = (rem & 31) * 32, k0 = (rem >> 5) * 32;
    const float* src = (z == 0) ? wq : (z == 1) ? wk : (z == 2) ? wv : wo;
    u16* dst = (z < 3) ? (wqkvT + (size_t)z * DIM * DIM) : woutT;
    const int tx = tid & 31, ty = tid >> 5;  // 32 x 8
#pragma unroll
    for (int i = 0; i < 4; i++)
      tile[ty + i * 8][tx] = src[(size_t)(k0 + ty + i * 8) * DIM + n0 + tx];
    __syncthreads();
#pragma unroll
    for (int i = 0; i < 4; i++)
      dst[(size_t)(n0 + ty + i * 8) * DIM + k0 + tx] = f2bf(tile[tx][ty + i * 8]);
    return;
  }
  // ---- RMSNorm + scorer + cnt zeroing ----
  const int row = b - 4096;
  const float4* xr = (const float4*)(x + (size_t)row * DIM);
  float4 v = xr[tid];
  float ss = v.x * v.x + v.y * v.y + v.z * v.z + v.w * v.w;
#pragma unroll
  for (int o = 32; o >= 1; o >>= 1) ss += __shfl_xor(ss, o);
  __shared__ float red[4], red2[4];
  int wv2 = tid >> 6;
  if ((tid & 63) == 0) red[wv2] = ss;
  __syncthreads();
  ss = red[0] + red[1] + red[2] + red[3];
  float rn = rsqrtf(ss * (1.0f / DIM) + 1e-6f);
  float4 w4 = ((const float4*)nw)[tid];
  float h0 = v.x * rn * w4.x, h1 = v.y * rn * w4.y;
  float h2 = v.z * rn * w4.z, h3 = v.w * rn * w4.w;
  uint64_t pack = (uint64_t)f2bf(h0) | ((uint64_t)f2bf(h1) << 16) |
                  ((uint64_t)f2bf(h2) << 32) | ((uint64_t)f2bf(h3) << 48);
  *(uint64_t*)(h + (size_t)row * DIM + tid * 4) = pack;
  float4 s4 = ((const float4*)sw)[tid];
  float sc = h0 * s4.x + h1 * s4.y + h2 * s4.z + h3 * s4.w;
#pragma unroll
  for (int o = 32; o >= 1; o >>= 1) sc += __shfl_xor(sc, o);
  if ((tid & 63) == 0) red2[wv2] = sc;
  __syncthreads();
  if (tid == 0) {
    scores[row] = red2[0] + red2[1] + red2[2] + red2[3] + sb[0];
    cnt[row] = 0;
  }
}

// ---------------- exact top-G by distributed rank counting ----------------
__global__ __launch_bounds__(256) void topk_count_kernel(
    const float* __restrict__ scores, int* __restrict__ cnt) {
  __shared__ float sj[1024];
  int jbase = blockIdx.y * 1024;
  for (int t = threadIdx.x; t < 1024; t += 256) sj[t] = scores[jbase + t];
  __syncthreads();
  int i = blockIdx.x * 256 + threadIdx.x;
  float my = scores[i];
  int c = 0;
  const float4* s4 = (const float4*)sj;
#pragma unroll 4
  for (int j = 0; j < 256; j++) {
    float4 v = s4[j];
    int b = jbase + j * 4;
    c += (v.x > my) || (v.x == my && (b + 0) < i);
    c += (v.y > my) || (v.y == my && (b + 1) < i);
    c += (v.z > my) || (v.z == my && (b + 2) < i);
    c += (v.w > my) || (v.w == my && (b + 3) < i);
  }
  if (c) atomicAdd(&cnt[i], c);
}

__global__ __launch_bounds__(256) void topk_scatter_kernel(
    const int* __restrict__ cnt, int* __restrict__ gidx) {
  int i = blockIdx.x * 256 + threadIdx.x;
  int c = cnt[i];
  if (c < GTOK) gidx[c] = i;
}

// ---------------- gather top-G K/V rows ----------------
__global__ __launch_bounds__(128) void gather_kernel(
    const u16* __restrict__ qkv, const int* __restrict__ gidx,
    u16* __restrict__ kg, u16* __restrict__ vg) {
  int g = blockIdx.x, t = threadIdx.x;
  size_t src = (size_t)gidx[g] * QKV_STRIDE;
  *(bf16x8*)(kg + (size_t)g * DIM + t * 8) = *(const bf16x8*)(qkv + src + DIM + t * 8);
  *(bf16x8*)(vg + (size_t)g * DIM + t * 8) = *(const bf16x8*)(qkv + src + 2 * DIM + t * 8);
}

// ---------------- GEMM 256Mx128N tile, 8 waves, BK=64, 3-buf 2-deep counted-vmcnt ----------------
// (round-8 exact version -- best measured GEMM)
template <int RESID>
__global__ __launch_bounds__(512, 2) void gemm256_kernel(
    const u16* __restrict__ A, const u16* __restrict__ B,
    u16* __restrict__ Cb, float* __restrict__ Cf, const float* __restrict__ X,
    int M, int N, int K) {
  __shared__ __align__(16) u16 As[3][256 * 64];
  __shared__ __align__(16) u16 Bs[3][128 * 64];
  const int tid = threadIdx.x;
  const int wave = tid >> 6, lane = tid & 63;
  const int l15 = lane & 15, l4 = lane >> 4;
  const int wr = wave >> 1, wc = wave & 1;  // 4M x 2N wave grid, 64x64 per wave
  const int mbase = blockIdx.x * 256, nbase = blockIdx.y * 128;
  const int srow = lane >> 3, schunk = lane & 7;
  const int gcol = (schunk ^ srow) * 8;

  auto stage = [&](int tt, int b) {
    const int kt = tt << 6;
#pragma unroll
    for (int q = 0; q < 4; q++) {
      int row = wave * 32 + q * 8;
      gload_lds16(A + (size_t)(mbase + row + srow) * K + kt + gcol, &As[b][row * 64]);
    }
#pragma unroll
    for (int q = 0; q < 2; q++) {
      int row = wave * 16 + q * 8;
      gload_lds16(B + (size_t)(nbase + row + srow) * K + kt + gcol, &Bs[b][row * 64]);
    }
  };

  const int nt = K >> 6;
  f32x4 acc[4][4] = {};

  stage(0, 0);
  stage(1, 1);
  asm volatile("s_waitcnt vmcnt(6)" ::: "memory");
  __builtin_amdgcn_s_barrier();
  __builtin_amdgcn_sched_barrier(0);

  int cur = 0;
  for (int t = 0; t < nt; t++) {
    int pre = cur + 2; if (pre >= 3) pre -= 3;
    if (t + 2 < nt) stage(t + 2, pre);
    const u16* Ab = &As[cur][0];
    const u16* Bb = &Bs[cur][0];
    bf16x8 bfr[4][2], af[4][2];
#pragma unroll
    for (int nf = 0; nf < 4; nf++) {
      int row = wc * 64 + nf * 16 + l15;
#pragma unroll
      for (int kk = 0; kk < 2; kk++)
        bfr[nf][kk] = *(const bf16x8*)(Bb + row * 64 + (((kk * 4 + l4) ^ (l15 & 7)) * 8));
    }
#pragma unroll
    for (int mi = 0; mi < 4; mi++) {
      int row = wr * 64 + mi * 16 + l15;
#pragma unroll
      for (int kk = 0; kk < 2; kk++)
        af[mi][kk] = *(const bf16x8*)(Ab + row * 64 + (((kk * 4 + l4) ^ (l15 & 7)) * 8));
    }
    __builtin_amdgcn_s_setprio(1);
#pragma unroll
    for (int mi = 0; mi < 4; mi++)
#pragma unroll
      for (int nf = 0; nf < 4; nf++)
#pragma unroll
        for (int kk = 0; kk < 2; kk++)
          acc[mi][nf] = __builtin_amdgcn_mfma_f32_16x16x32_bf16(af[mi][kk], bfr[nf][kk],
                                                                acc[mi][nf], 0, 0, 0);
    __builtin_amdgcn_s_setprio(0);
    if (t + 1 < nt) {
      if (t + 2 < nt) asm volatile("s_waitcnt vmcnt(6)" ::: "memory");
      else            asm volatile("s_waitcnt vmcnt(0)" ::: "memory");
      __builtin_amdgcn_s_barrier();
      __builtin_amdgcn_sched_barrier(0);
    }
    cur = (cur + 1 == 3) ? 0 : cur + 1;
  }

#pragma unroll
  for (int mi = 0; mi < 4; mi++) {
#pragma unroll
    for (int nf = 0; nf < 4; nf++) {
#pragma unroll
      for (int r = 0; r < 4; r++) {
        int row = mbase + wr * 64 + mi * 16 + l4 * 4 + r;
        int col = nbase + wc * 64 + nf * 16 + l15;
        float v = acc[mi][nf][r];
        if (RESID) Cf[(size_t)row * N + col] = X[(size_t)row * N + col] + v;
        else       Cb[(size_t)row * N + col] = f2bf(v);
      }
    }
  }
}

// ---------------- fused flash attention (r15: KVBLK=128, 2-shfl pack) ----------------
__global__ __launch_bounds__(512) void attn_kernel(
    const u16* __restrict__ qkv, const u16* __restrict__ kg,
    const u16* __restrict__ vg, const int* __restrict__ gidx,
    u16* __restrict__ o) {
  __shared__ u16 kT[2][128][72];   // [buf][key][d] (+8 pad)
  __shared__ u16 vT[2][64][136];   // [buf][d][key-halfXOR] (+8 pad)
  __shared__ int gposLds[2][128];
  const int tid = threadIdx.x, wave = tid >> 6, lane = tid & 63;
  const int l31 = lane & 31, hi = lane >> 5;
  const int win = blockIdx.x >> 1, pair = blockIdx.x & 1;
  const int wbase = win * WIN;
  const int hoff = blockIdx.y * HD;

  const int skey = tid >> 3, sd8 = (tid & 7) * 8;
  const int vcol = skey ^ ((sd8 >> 4) << 4);

  bf16x8 nk0, nk1, nv0, nv1;
  int ng = 0;
  {
    const u16* b0 = qkv + (size_t)(wbase + skey) * QKV_STRIDE + hoff + sd8;
    const u16* b1 = qkv + (size_t)(wbase + 64 + skey) * QKV_STRIDE + hoff + sd8;
    nk0 = *(const bf16x8*)(b0 + DIM);     nv0 = *(const bf16x8*)(b0 + 2 * DIM);
    nk1 = *(const bf16x8*)(b1 + DIM);     nv1 = *(const bf16x8*)(b1 + 2 * DIM);
  }

  for (int sp = 0; sp < 2; sp++) {
    const int j = sp ? (3 - pair) : pair;
    const int qsbase = wbase + j * 256;
    const int nLocal = (j + 1) * 2;
    const int nTiles = nLocal + GTOK / 128;
    const int qrow = qsbase + wave * 32 + l31;
    const int qwmax = qsbase + wave * 32 + 31;

    bf16x8 qf[4];
    {
      const float SC2 = 0.125f * 1.44269504088896f;
      const u16* qptr = qkv + (size_t)qrow * QKV_STRIDE + hoff + hi * 8;
#pragma unroll
      for (int ks = 0; ks < 4; ks++) {
        bf16x8 raw = *(const bf16x8*)(qptr + ks * 16);
        bf16x8 sc;
#pragma unroll
        for (int jj = 0; jj < 8; jj++) sc[jj] = (short)f2bf(bf2f((u16)raw[jj]) * SC2);
        qf[ks] = sc;
      }
    }

    f32x16 acc0 = {}, acc1 = {};
    float mr = -3.0e38f, lr = 0.f;

    __syncthreads();

    for (int t = 0; t < nTiles; t++) {
      const int p = t & 1;
      const bool isLocal = (t < nLocal);
      *(bf16x8*)(&kT[p][skey][sd8]) = nk0;
      *(bf16x8*)(&kT[p][64 + skey][sd8]) = nk1;
#pragma unroll
      for (int jj = 0; jj < 8; jj++) {
        vT[p][sd8 + jj][vcol] = (u16)nv0[jj];
        vT[p][sd8 + jj][64 + vcol] = (u16)nv1[jj];
      }
      if (!isLocal && tid < 128) gposLds[p][tid] = ng;
      {
        const int nt = t + 1;
        const u16 *k0s = nullptr, *k1s = nullptr, *v0s = nullptr, *v1s = nullptr;
        if (nt < nLocal) {
          const u16* b0 = qkv + (size_t)(wbase + nt * 128 + skey) * QKV_STRIDE + hoff + sd8;
          const u16* b1 = b0 + (size_t)64 * QKV_STRIDE;
          k0s = b0 + DIM; v0s = b0 + 2 * DIM;
          k1s = b1 + DIM; v1s = b1 + 2 * DIM;
        } else if (nt < nTiles) {
          size_t g0 = (size_t)((nt - nLocal) * 128 + skey) * DIM + hoff + sd8;
          k0s = kg + g0; v0s = vg + g0;
          k1s = kg + g0 + (size_t)64 * DIM; v1s = vg + g0 + (size_t)64 * DIM;
          if (tid < 128) ng = gidx[(nt - nLocal) * 128 + tid];
        } else if (sp == 0) {
          const u16* b0 = qkv + (size_t)(wbase + skey) * QKV_STRIDE + hoff + sd8;
          const u16* b1 = b0 + (size_t)64 * QKV_STRIDE;
          k0s = b0 + DIM; v0s = b0 + 2 * DIM;
          k1s = b1 + DIM; v1s = b1 + 2 * DIM;
        }
        if (k0s) {
          nk0 = *(const bf16x8*)(k0s); nv0 = *(const bf16x8*)(v0s);
          nk1 = *(const bf16x8*)(k1s); nv1 = *(const bf16x8*)(v1s);
        }
      }
      __syncthreads();

#pragma unroll
      for (int sub = 0; sub < 2; sub++) {
        const int tbase = wbase + t * 128 + sub * 64;
        if (isLocal && tbase > qwmax) continue;

        float sv[32];
        __builtin_amdgcn_s_setprio(1);
#pragma unroll
        for (int kb = 0; kb < 2; kb++) {
          const u16* krow = &kT[p][sub * 64 + kb * 32 + l31][hi * 8];
          bf16x8 k0 = *(const bf16x8*)(krow);
          bf16x8 k1 = *(const bf16x8*)(krow + 16);
          bf16x8 k2 = *(const bf16x8*)(krow + 32);
          bf16x8 k3 = *(const bf16x8*)(krow + 48);
          f32x16 z = {};
          z = __builtin_amdgcn_mfma_f32_32x32x16_bf16(k0, qf[0], z, 0, 0, 0);
          z = __builtin_amdgcn_mfma_f32_32x32x16_bf16(k1, qf[1], z, 0, 0, 0);
          z = __builtin_amdgcn_mfma_f32_32x32x16_bf16(k2, qf[2], z, 0, 0, 0);
          z = __builtin_amdgcn_mfma_f32_32x32x16_bf16(k3, qf[3], z, 0, 0, 0);
#pragma unroll
          for (int r = 0; r < 16; r++) sv[kb * 16 + r] = z[r];
        }
        __builtin_amdgcn_s_setprio(0);

        if (isLocal) {
          const int lim = qrow - tbase;
          if (lim < 63) {
#pragma unroll
            for (int kb = 0; kb < 2; kb++)
#pragma unroll
              for (int r = 0; r < 16; r++) {
                int crow = kb * 32 + (r & 3) + 8 * (r >> 2) + 4 * hi;
                if (crow > lim) sv[kb * 16 + r] = -3.0e38f;
              }
          }
        } else {
#pragma unroll
          for (int kb = 0; kb < 2; kb++)
#pragma unroll
            for (int r = 0; r < 16; r++) {
              int kpos = gposLds[p][sub * 64 + kb * 32 + (r & 3) + 8 * (r >> 2) + 4 * hi];
              if (kpos > qrow) sv[kb * 16 + r] = -3.0e38f;
            }
        }

        float m0 = sv[0], m1 = sv[1], m2 = sv[2], m3 = sv[3];
#pragma unroll
        for (int i = 4; i < 32; i += 4) {
          m0 = fmaxf(m0, sv[i]);     m1 = fmaxf(m1, sv[i + 1]);
          m2 = fmaxf(m2, sv[i + 2]); m3 = fmaxf(m3, sv[i + 3]);
        }
        float vmax = fmaxf(fmaxf(m0, m1), fmaxf(m2, m3));
        vmax = fmaxf(vmax, __shfl_xor(vmax, 32));
        if (__any(vmax > mr + 11.0f)) {
          float mn = fmaxf(mr, vmax);
          float al = exp2f(mr - mn);
          lr *= al;
          mr = mn;
#pragma unroll
          for (int i = 0; i < 16; i++) { acc0[i] *= al; acc1[i] *= al; }
        }
        float s0 = 0.f, s1 = 0.f, s2 = 0.f, s3 = 0.f;
#pragma unroll
        for (int i = 0; i < 32; i += 4) {
          float p0 = exp2f(sv[i] - mr),     p1 = exp2f(sv[i + 1] - mr);
          float p2 = exp2f(sv[i + 2] - mr), p3 = exp2f(sv[i + 3] - mr);
          sv[i] = p0; sv[i + 1] = p1; sv[i + 2] = p2; sv[i + 3] = p3;
          s0 += p0; s1 += p1; s2 += p2; s3 += p3;
        }
        float ps = (s0 + s1) + (s2 + s3);
        ps += __shfl_xor(ps, 32);
        lr += ps;

        bf16x8 pf[4];
#pragma unroll
        for (int q4 = 0; q4 < 4; q4++) {
          int b = q4 * 8;
          uint32_t w0 = cvtpk(sv[b + 0], sv[b + 1]);
          uint32_t w1 = cvtpk(sv[b + 2], sv[b + 3]);
          uint32_t w2 = cvtpk(sv[b + 4], sv[b + 5]);
          uint32_t w3 = cvtpk(sv[b + 6], sv[b + 7]);
          uint32_t x1 = hi ? w0 : w2;
          uint32_t x2 = hi ? w1 : w3;
          uint32_t r1 = (uint32_t)__shfl_xor((int)x1, 32);
          uint32_t r2 = (uint32_t)__shfl_xor((int)x2, 32);
          union { uint32_t w[4]; bf16x8 v; } u;
          u.w[0] = hi ? r1 : w0;
          u.w[1] = hi ? r2 : w1;
          u.w[2] = hi ? w2 : r1;
          u.w[3] = hi ? w3 : r2;
          pf[q4] = u.v;
        }

        __builtin_amdgcn_s_setprio(1);
#pragma unroll
        for (int dblk = 0; dblk < 2; dblk++) {
          const int swz = (dblk * 2 + (l31 >> 4)) << 4;
          const u16* vrow = &vT[p][dblk * 32 + l31][sub * 64];
          f32x16 a = dblk ? acc1 : acc0;
#pragma unroll
          for (int ksg = 0; ksg < 4; ksg++) {
            bf16x8 vf = *(const bf16x8*)(vrow + ((ksg * 16 + hi * 8) ^ swz));
            a = __builtin_amdgcn_mfma_f32_32x32x16_bf16(vf, pf[ksg], a, 0, 0, 0);
          }
          if (dblk) acc1 = a; else acc0 = a;
        }
        __builtin_amdgcn_s_setprio(0);
      }
    }

    float inv = 1.0f / lr;
#pragma unroll
    for (int dblk = 0; dblk < 2; dblk++) {
      f32x16 a = dblk ? acc1 : acc0;
#pragma unroll
      for (int g = 0; g < 4; g++) {
        uint64_t pk = (uint64_t)f2bf(a[g * 4 + 0] * inv)
                    | ((uint64_t)f2bf(a[g * 4 + 1] * inv) << 16)
                    | ((uint64_t)f2bf(a[g * 4 + 2] * inv) << 32)
                    | ((uint64_t)f2bf(a[g * 4 + 3] * inv) << 48);
        *(uint64_t*)(o + (size_t)qrow * DIM + hoff + dblk * 32 + g * 8 + 4 * hi) = pk;
      }
    }
  }
}

// ---------------- launch ----------------
extern "C" void kernel_launch(void* const* d_in, const int* in_sizes, int n_in,
                              void* d_out, int out_size, void* d_ws, size_t ws_size,
                              hipStream_t stream) {
  const float* x  = (const float*)d_in[0];
  const float* nw = (const float*)d_in[1];
  const float* wq = (const float*)d_in[2];
  const float* wk = (const float*)d_in[3];
  const float* wv = (const float*)d_in[4];
  const float* wo = (const float*)d_in[5];
  const float* sw = (const float*)d_in[6];
  const float* sb = (const float*)d_in[7];
  float* out = (float*)d_out;

  char* ws = (char*)d_ws;
  size_t off = 0;
  auto alloc = [&](size_t b) {
    char* p = ws + off;
    off = (off + b + 255) & ~(size_t)255;
    return p;
  };
  u16*   h      = (u16*)alloc((size_t)S_LEN * DIM * 2);
  u16*   wqkvT  = (u16*)alloc((size_t)3 * DIM * DIM * 2);
  u16*   woutT  = (u16*)alloc((size_t)DIM * DIM * 2);
  u16*   qkv    = (u16*)alloc((size_t)S_LEN * 3 * DIM * 2);
  u16*   obuf   = (u16*)alloc((size_t)S_LEN * DIM * 2);
  float* scores = (float*)alloc((size_t)S_LEN * 4);
  int*   cnt    = (int*)alloc((size_t)S_LEN * 4);
  int*   gidx   = (int*)alloc((size_t)GTOK * 4);
  u16*   kgbuf  = (u16*)alloc((size_t)GTOK * DIM * 2);
  u16*   vgbuf  = (u16*)alloc((size_t)GTOK * DIM * 2);

  prep_kernel<<<dim3(4096 + S_LEN), dim3(256), 0, stream>>>(
      x, nw, sw, sb, wq, wk, wv, wo, h, scores, cnt, wqkvT, woutT);
  topk_count_kernel<<<dim3(32, 8), dim3(256), 0, stream>>>(scores, cnt);
  topk_scatter_kernel<<<dim3(S_LEN / 256), dim3(256), 0, stream>>>(cnt, gidx);
  gemm256_kernel<0><<<dim3(32, 24), dim3(512), 0, stream>>>(h, wqkvT, qkv, nullptr, nullptr,
                                                            S_LEN, 3 * DIM, DIM);
  gather_kernel<<<dim3(GTOK), dim3(128), 0, stream>>>(qkv, gidx, kgbuf, vgbuf);
  attn_kernel<<<dim3(16, NH), dim3(512), 0, stream>>>(qkv, kgbuf, vgbuf, gidx, obuf);
  gemm256_kernel<1><<<dim3(32, 8), dim3(512), 0, stream>>>(obuf, woutT, nullptr, out, x,
                                                           S_LEN, DIM, DIM);
}